// Round 6
// baseline (127.342 us; speedup 1.0000x reference)
//
#include <hip/hip_runtime.h>

namespace {
constexpr int N = 1024;
constexpr int D = 128;
constexpr int E = 32768;
constexpr int TILE = 2;      // nodes per fused block -> grid = 512 = 2 blocks/CU

// ---- one-block edge build: counts+deg (LDS atomics), shfl scan, bucket fill ----
__global__ __launch_bounds__(1024) void k_edges(const int* __restrict__ ei,
    int* __restrict__ off, int* __restrict__ deg, int* __restrict__ bucket){
  __shared__ int scnt[N], sdeg[N], scur[N];
  __shared__ int wsum[16];
  int t = threadIdx.x;
  scnt[t] = 0; sdeg[t] = 0;
  __syncthreads();
  #pragma unroll
  for(int it = 0; it < E/1024; ++it){
    int e = it*1024 + t;
    int s = ei[e], d = ei[E+e];
    atomicAdd(&scnt[d], 1);
    atomicAdd(&sdeg[s], 1);
    atomicAdd(&sdeg[d], 1);
  }
  __syncthreads();
  deg[t] = sdeg[t];
  int v = scnt[t], own = v;
  int lane = t & 63, w = t >> 6;
  #pragma unroll
  for(int o2 = 1; o2 < 64; o2 <<= 1){
    int nb = __shfl_up(v, o2, 64);
    if(lane >= o2) v += nb;
  }
  if(lane == 63) wsum[w] = v;
  __syncthreads();
  int pref = 0;
  #pragma unroll
  for(int i = 0; i < 16; ++i){ int sv = wsum[i]; if(i < w) pref += sv; }
  int incl = v + pref, excl = incl - own;
  off[t] = excl; scur[t] = excl;
  if(t == N-1) off[N] = incl;
  __syncthreads();
  #pragma unroll
  for(int it = 0; it < E/1024; ++it){
    int e = it*1024 + t;
    int s = ei[e], d = ei[E+e];
    int p = atomicAdd(&scur[d], 1);
    bucket[p] = s;
  }
}

// ---- neighbor mean: 512 blocks x 256 thr, 2 nodes/block ----
__global__ __launch_bounds__(256) void k_mean(const float* __restrict__ x,
    const int* __restrict__ off, const int* __restrict__ bucket,
    float* __restrict__ mean){
  int t = threadIdx.x;
  int f = t & 127, hh = t >> 7;
  int n = blockIdx.x*2 + hh;
  int beg = off[n], end = off[n+1];
  float a0=0.f, a1=0.f, a2=0.f, a3=0.f;
  int j = beg;
  for(; j+3 < end; j += 4){
    int i0=bucket[j], i1=bucket[j+1], i2=bucket[j+2], i3=bucket[j+3];
    a0 += x[i0*D+f]; a1 += x[i1*D+f]; a2 += x[i2*D+f]; a3 += x[i3*D+f];
  }
  for(; j < end; ++j) a0 += x[bucket[j]*D+f];
  int c = end - beg;
  mean[n*D + f] = (a0+a1+a2+a3) / (float)(c>1?c:1);
}

// ---- fused GEMM chain, TILE=2, reg-staged swizzled LDS weights ----
// 512 blocks x 256 thr (4 waves). thread = (m = f-pair 0..63, kq = k-quarter 0..3).
// Per thread: 2 features x 2 nodes x 8 k per 32k-chunk. Weight chunk [128][32]
// lives in LDS with column XOR-swizzle: sW[r*32+cq*4+j] = M[r][kc*32+(cq^s(r))*4+j],
// s(r) = (r>>1)&7; read slot = (kq*2+k4)^(m&7). Conflict-free b128 both sides.
__global__ __launch_bounds__(256, 2) void k_fused(
    const float* __restrict__ x, const float* __restrict__ mean,
    const float* __restrict__ Wl, const float* __restrict__ bl,
    const float* __restrict__ Wr,
    const float* __restrict__ W1, const float* __restrict__ b1,
    const float* __restrict__ W2, const float* __restrict__ b2,
    const float* __restrict__ Wp, const float* __restrict__ Wd,
    const float* __restrict__ bd, const int* __restrict__ deg,
    float* __restrict__ delta, float* __restrict__ res,
    float* __restrict__ scores, float* __restrict__ s1, float* __restrict__ s2)
{
  __shared__ float sW[2][128*32];
  __shared__ float sx[TILE][D], smean[TILE][D], sxg[TILE][D], sdr[TILE][D];
  __shared__ float cscr[4][64][4];
  int t = threadIdx.x;
  int base = blockIdx.x * TILE;
  int m = t & 63, kq = t >> 6;
  int f0 = m*2;

  const float* WpA = Wp;
  const float* WpC = Wp + 2*D*D;
  const float* WpR = Wp + 3*D*D;

  float4 tmp[4];
  auto stage_load = [&](int ns){
    int nm = ns >> 2, nkc = ns & 3;
    const float* M = nm==0?Wl: nm==1?Wr: nm==2?WpA: nm==3?WpC: nm==4?WpR: Wd;
    #pragma unroll
    for(int ii = 0; ii < 4; ++ii){
      int r = ii*32 + (t>>3);
      int cq = t & 7;
      int cg = cq ^ ((r>>1)&7);
      tmp[ii] = *(const float4*)&M[r*D + nkc*32 + cg*4];
    }
  };
  auto stage_write = [&](int pbuf){
    #pragma unroll
    for(int ii = 0; ii < 4; ++ii){
      int r = ii*32 + (t>>3);
      int cq = t & 7;
      *(float4*)&sW[pbuf][r*32 + cq*4] = tmp[ii];
    }
  };

  // prologue: chunk 0 + activation tiles
  stage_load(0);
  if(t < 64)       *(float4*)(&sx[0][0]    + t*4)      = *(const float4*)&x[base*D + t*4];
  else if(t < 128) *(float4*)(&smean[0][0] + (t-64)*4) = *(const float4*)&mean[base*D + (t-64)*4];
  stage_write(0);
  __syncthreads();

  float acc[2][2] = {{0,0},{0,0}};   // [ff][p]
  float gg[2][2];
  int buf = 0;
  for(int s = 0; s < 24; ++s){
    int mm = s >> 2, kc = s & 3;
    if(s < 23) stage_load(s+1);      // issue early (T14)
    const float (*sIn)[D] = (mm==0)?smean:(mm==1)?sx:(mm<5)?sxg:sdr;
    const float* wb = sW[buf];
    #pragma unroll
    for(int k4 = 0; k4 < 2; ++k4){
      int slot = (kq*2 + k4) ^ (m & 7);
      float4 w0 = *(const float4*)&wb[f0*32 + slot*4];
      float4 w1 = *(const float4*)&wb[(f0+1)*32 + slot*4];
      int kx = kc*32 + kq*8 + k4*4;
      #pragma unroll
      for(int p = 0; p < 2; ++p){
        float4 vv = *(const float4*)&sIn[p][kx];
        acc[0][p] += vv.x*w0.x + vv.y*w0.y + vv.z*w0.z + vv.w*w0.w;
        acc[1][p] += vv.x*w1.x + vv.y*w1.y + vv.z*w1.z + vv.w*w1.w;
      }
    }
    if(s < 23) stage_write(buf^1);   // consume staged regs (write-late)
    if((s & 3) == 3 && s >= 7){
      // combine the 4 k-quarters via LDS scratch
      *(float4*)&cscr[kq][m][0] = make_float4(acc[0][0], acc[0][1], acc[1][0], acc[1][1]);
      __syncthreads();
      #pragma unroll
      for(int q = 1; q < 4; ++q){
        float4 o = *(const float4*)&cscr[(kq+q)&3][m][0];
        acc[0][0]+=o.x; acc[0][1]+=o.y; acc[1][0]+=o.z; acc[1][1]+=o.w;
      }
      if(s == 7){                 // gelu(mean@Wl^T + x@Wr^T + bl + x)
        float2 blv = *(const float2*)&bl[f0];
        #pragma unroll
        for(int p = 0; p < 2; ++p){
          float v0 = acc[0][p] + blv.x + sx[p][f0];
          float v1 = acc[1][p] + blv.y + sx[p][f0+1];
          float g0 = 0.5f*v0*(1.0f + erff(v0*0.7071067811865475f));
          float g1 = 0.5f*v1*(1.0f + erff(v1*0.7071067811865475f));
          gg[0][p] = g0; gg[1][p] = g1;
          if(kq == 0){ sxg[p][f0] = g0; sxg[p][f0+1] = g1; }
        }
      } else if(s == 11){         // delta_raw -> sdr
        if(kq == 0){
          #pragma unroll
          for(int p = 0; p < 2; ++p){ sdr[p][f0] = acc[0][p]; sdr[p][f0+1] = acc[1][p]; }
        }
      } else if(s == 15){         // Cs -> S1/S2
        if(kq == 0){
          atomicAdd(&s1[f0],   gg[0][0]*acc[0][0] + gg[0][1]*acc[0][1]);
          atomicAdd(&s1[f0+1], gg[1][0]*acc[1][0] + gg[1][1]*acc[1][1]);
          atomicAdd(&s2[f0],   acc[0][0] + acc[0][1]);
          atomicAdd(&s2[f0+1], acc[1][0] + acc[1][1]);
        }
      } else if(s == 19){         // residual
        if(kq == 0){
          #pragma unroll
          for(int p = 0; p < 2; ++p){
            float2 rv; rv.x = acc[0][p]; rv.y = acc[1][p];
            *(float2*)&res[(base+p)*D + f0] = rv;
          }
        }
      } else {                    // s == 23: delta = softplus(. + bd)
        if(kq == 0){
          float2 bdv = *(const float2*)&bd[f0];
          #pragma unroll
          for(int p = 0; p < 2; ++p){
            float d0 = acc[0][p] + bdv.x, d1 = acc[1][p] + bdv.y;
            float sp0 = (d0 > 20.f) ? d0 : log1pf(expf(d0));
            float sp1 = (d1 > 20.f) ? d1 : log1pf(expf(d1));
            float2 dv; dv.x = sp0; dv.y = sp1;
            *(float2*)&delta[(base+p)*D + f0] = dv;
          }
        }
      }
      acc[0][0]=0.f; acc[0][1]=0.f; acc[1][0]=0.f; acc[1][1]=0.f;
    }
    __syncthreads();
    buf ^= 1;
  }

  // scores MLP (R=32) + deg : threads 0..63 (p = t>>5 in 0..1, r = t&31)
  if(t < 64){
    int r = t & 31, p = t >> 5;
    float h = 0.f;
    #pragma unroll
    for(int k4 = 0; k4 < 32; ++k4){
      float4 w = *(const float4*)&W1[r*D + k4*4];
      float4 g = *(const float4*)&sxg[p][k4*4];
      h += g.x*w.x + g.y*w.y + g.z*w.z + g.w*w.w;
    }
    h += b1[r];
    h = fmaxf(h, 0.f);
    float part = h * W2[r];
    part += __shfl_down(part, 16, 32);
    part += __shfl_down(part, 8, 32);
    part += __shfl_down(part, 4, 32);
    part += __shfl_down(part, 2, 32);
    part += __shfl_down(part, 1, 32);
    if(r == 0) scores[base + p] = part + b2[0] + (float)deg[base + p];
  }
}

__device__ __forceinline__ unsigned long long shflx64(unsigned long long v, int mask){
  int lo = __shfl_xor((int)(v & 0xffffffffull), mask);
  int hi = __shfl_xor((int)(v >> 32), mask);
  return ((unsigned long long)(unsigned int)hi << 32) | (unsigned int)lo;
}

// ---- hybrid bitonic argsort: j>=64 via LDS+barrier, j<=32 in-register shfl ----
__global__ __launch_bounds__(1024) void k_sort(const float* __restrict__ scores, int* sidx){
  __shared__ unsigned long long keys[N];
  int t = threadIdx.x;
  unsigned int u = __float_as_uint(scores[t]);
  u = (u >> 31) ? ~u : (u | 0x80000000u);    // monotone float->uint (ascending)
  unsigned int ks = ~u;                       // descending score
  keys[t] = ((unsigned long long)ks << 32) | (unsigned int)t;
  __syncthreads();
  for(int k = 2; k <= N; k <<= 1){
    for(int j = k >> 1; j >= 64; j >>= 1){
      int ixj = t ^ j;
      if(ixj > t){
        bool up = ((t & k) == 0);
        unsigned long long a = keys[t], b = keys[ixj];
        if((a > b) == up){ keys[t] = b; keys[ixj] = a; }
      }
      __syncthreads();
    }
    unsigned long long kv = keys[t];
    bool up = ((t & k) == 0);
    for(int j = ((k>>1) < 32 ? (k>>1) : 32); j >= 1; j >>= 1){
      unsigned long long pv = shflx64(kv, j);
      bool lower = ((t & j) == 0);
      unsigned long long mn = kv < pv ? kv : pv;
      unsigned long long mx = kv < pv ? pv : kv;
      kv = (lower == up) ? mn : mx;
    }
    keys[t] = kv;
    __syncthreads();
  }
  sidx[t] = (int)(keys[t] & 0xFFFFFFFFu);
}

// ---- cumsum over sorted order, 4 heads/block; output pfx[l*D+h] ----
__global__ __launch_bounds__(1024) void k_cumsum(const float* __restrict__ delta,
     const int* __restrict__ sidx, const float* __restrict__ Bp, float* __restrict__ pfx){
  int t = threadIdx.x, h0 = blockIdx.x*4;
  int i = sidx[t];
  float4 dv = *(const float4*)&delta[i*D + h0];
  float4 bv = *(const float4*)&Bp[h0];
  float v0 = dv.x*bv.x, v1 = dv.y*bv.y, v2 = dv.z*bv.z, v3 = dv.w*bv.w;
  int lane = t & 63, w = t >> 6;
  #pragma unroll
  for(int o2 = 1; o2 < 64; o2 <<= 1){
    float n0 = __shfl_up(v0, o2, 64), n1 = __shfl_up(v1, o2, 64);
    float n2 = __shfl_up(v2, o2, 64), n3 = __shfl_up(v3, o2, 64);
    if(lane >= o2){ v0 += n0; v1 += n1; v2 += n2; v3 += n3; }
  }
  __shared__ float4 wsum[16];
  if(lane == 63) wsum[w] = make_float4(v0, v1, v2, v3);
  __syncthreads();
  float p0=0.f, p1=0.f, p2=0.f, p3=0.f;
  #pragma unroll
  for(int i2 = 0; i2 < 16; ++i2){
    float4 sv = wsum[i2];
    if(i2 < w){ p0 += sv.x; p1 += sv.y; p2 += sv.z; p3 += sv.w; }
  }
  float4 outv; outv.x = v0+p0; outv.y = v1+p1; outv.z = v2+p2; outv.w = v3+p3;
  *(float4*)&pfx[t*D + h0] = outv;   // layout [l][h]: k_final reads coalesced
}

// ---- final: y + res*Dp, LayerNorm over D, un-permute, add x ----
__global__ __launch_bounds__(128) void k_final(
    const float* __restrict__ delta, const float* __restrict__ res,
    const float* __restrict__ pfx, const int* __restrict__ sidx,
    const float* __restrict__ s1, const float* __restrict__ s2,
    const float* __restrict__ A, const float* __restrict__ Bp,
    const float* __restrict__ Dp, const float* __restrict__ x,
    float* __restrict__ out){
  int l = blockIdx.x, h = threadIdx.x;
  int i = sidx[l];
  float dlt = delta[i*D + h];
  float dAv = expf(dlt * A[h]) * Bp[h];
  float o = dAv * s1[h] + pfx[l*D + h] * s2[h] + res[i*D + h] * Dp[0];
  __shared__ float sm1[2], sm2[2];
  float v = o;
  v += __shfl_down(v, 32); v += __shfl_down(v, 16); v += __shfl_down(v, 8);
  v += __shfl_down(v, 4);  v += __shfl_down(v, 2);  v += __shfl_down(v, 1);
  int wid = h >> 6, lane = h & 63;
  if(lane == 0) sm1[wid] = v;
  __syncthreads();
  float mean = (sm1[0] + sm1[1]) * (1.0f/(float)D);
  float cdev = o - mean;
  float cv = cdev * cdev;
  cv += __shfl_down(cv, 32); cv += __shfl_down(cv, 16); cv += __shfl_down(cv, 8);
  cv += __shfl_down(cv, 4);  cv += __shfl_down(cv, 2);  cv += __shfl_down(cv, 1);
  if(lane == 0) sm2[wid] = cv;
  __syncthreads();
  float var = (sm2[0] + sm2[1]) * (1.0f/(float)D);
  float nrm = cdev * rsqrtf(var + 1e-5f);
  out[i*D + h] = x[i*D + h] + nrm;
}

} // namespace

extern "C" void kernel_launch(void* const* d_in, const int* in_sizes, int n_in,
                              void* d_out, int out_size, void* d_ws, size_t ws_size,
                              hipStream_t stream){
  const float* x   = (const float*)d_in[0];
  const int*   ei  = (const int*)d_in[1];
  const float* Wl  = (const float*)d_in[2];
  const float* bl  = (const float*)d_in[3];
  const float* Wr  = (const float*)d_in[4];
  const float* W1  = (const float*)d_in[5];
  const float* b1  = (const float*)d_in[6];
  const float* W2  = (const float*)d_in[7];
  const float* b2  = (const float*)d_in[8];
  const float* Wp  = (const float*)d_in[9];
  const float* A   = (const float*)d_in[10];
  const float* Bp  = (const float*)d_in[11];
  const float* Dp  = (const float*)d_in[12];
  const float* Wd  = (const float*)d_in[13];
  const float* bd  = (const float*)d_in[14];

  char* ws = (char*)d_ws;
  size_t o = 0;
  auto alloc = [&](size_t bytes)->char*{
    char* p = ws + o;
    o = (o + bytes + 255) & ~(size_t)255;
    return p;
  };
  // zero-initialized region (one memset): S1, S2
  float* s1     = (float*)alloc(D*4);
  float* s2     = (float*)alloc(D*4);
  size_t zbytes = o;
  int*   off    = (int*)  alloc((N+1)*4);
  int*   deg    = (int*)  alloc(N*4);
  int*   bucket = (int*)  alloc(E*4);
  float* meanb  = (float*)alloc((size_t)N*D*4);
  float* scores = (float*)alloc(N*4);
  int*   sidx   = (int*)  alloc(N*4);
  float* delta  = (float*)alloc((size_t)N*D*4);
  float* res    = (float*)alloc((size_t)N*D*4);
  float* pfx    = (float*)alloc((size_t)N*D*4);
  (void)ws_size; (void)in_sizes; (void)n_in; (void)out_size;

  hipMemsetAsync(d_ws, 0, zbytes, stream);
  k_edges <<<1, 1024, 0, stream>>>(ei, off, deg, bucket);
  k_mean  <<<N/2, 256, 0, stream>>>(x, off, bucket, meanb);
  k_fused <<<N/TILE, 256, 0, stream>>>(x, meanb, Wl, bl, Wr, W1, b1, W2, b2, Wp, Wd, bd,
                                       deg, delta, res, scores, s1, s2);
  k_sort  <<<1, 1024, 0, stream>>>(scores, sidx);
  k_cumsum<<<D/4, 1024, 0, stream>>>(delta, sidx, Bp, pfx);
  k_final <<<N, 128, 0, stream>>>(delta, res, pfx, sidx, s1, s2, A, Bp, Dp, x, (float*)d_out);
}

// Round 7
// 85.840 us; speedup vs baseline: 1.4835x; 1.4835x over previous
//
#include <hip/hip_runtime.h>

namespace {
constexpr int N = 1024;
constexpr int D = 128;
constexpr int E = 32768;

using short8  = __attribute__((ext_vector_type(8))) short;
using floatx4 = __attribute__((ext_vector_type(4))) float;

__device__ __forceinline__ unsigned short f2bf(float f){
  unsigned int u = __float_as_uint(f);
  unsigned int r = (u + 0x7FFFu + ((u >> 16) & 1u)) >> 16;   // RTN-even
  return (unsigned short)r;
}
__device__ __forceinline__ float bf2f(unsigned short b){
  return __uint_as_float(((unsigned int)b) << 16);
}
// 8 consecutive f32 -> bf16x8 fragment
__device__ __forceinline__ short8 ldfrag(const float* p){
  float4 a = *(const float4*)p;
  float4 b = *(const float4*)(p + 4);
  short8 r;
  r[0]=(short)f2bf(a.x); r[1]=(short)f2bf(a.y); r[2]=(short)f2bf(a.z); r[3]=(short)f2bf(a.w);
  r[4]=(short)f2bf(b.x); r[5]=(short)f2bf(b.y); r[6]=(short)f2bf(b.z); r[7]=(short)f2bf(b.w);
  return r;
}

// ---- one-block edge build: counts+deg (LDS atomics), shfl scan, bucket fill ----
__global__ __launch_bounds__(1024) void k_edges(const int* __restrict__ ei,
    int* __restrict__ off, int* __restrict__ deg, int* __restrict__ bucket){
  __shared__ int scnt[N], sdeg[N], scur[N];
  __shared__ int wsum[16];
  int t = threadIdx.x;
  scnt[t] = 0; sdeg[t] = 0;
  __syncthreads();
  #pragma unroll
  for(int it = 0; it < E/1024; ++it){
    int e = it*1024 + t;
    int s = ei[e], d = ei[E+e];
    atomicAdd(&scnt[d], 1);
    atomicAdd(&sdeg[s], 1);
    atomicAdd(&sdeg[d], 1);
  }
  __syncthreads();
  deg[t] = sdeg[t];
  int v = scnt[t], own = v;
  int lane = t & 63, w = t >> 6;
  #pragma unroll
  for(int o2 = 1; o2 < 64; o2 <<= 1){
    int nb = __shfl_up(v, o2, 64);
    if(lane >= o2) v += nb;
  }
  if(lane == 63) wsum[w] = v;
  __syncthreads();
  int pref = 0;
  #pragma unroll
  for(int i = 0; i < 16; ++i){ int sv = wsum[i]; if(i < w) pref += sv; }
  int incl = v + pref, excl = incl - own;
  off[t] = excl; scur[t] = excl;
  if(t == N-1) off[N] = incl;
  __syncthreads();
  #pragma unroll
  for(int it = 0; it < E/1024; ++it){
    int e = it*1024 + t;
    int s = ei[e], d = ei[E+e];
    int p = atomicAdd(&scur[d], 1);
    bucket[p] = s;
  }
}

// ---- neighbor mean: 512 blocks x 256 thr, 2 nodes/block ----
__global__ __launch_bounds__(256) void k_mean(const float* __restrict__ x,
    const int* __restrict__ off, const int* __restrict__ bucket,
    float* __restrict__ mean){
  int t = threadIdx.x;
  int f = t & 127, hh = t >> 7;
  int n = blockIdx.x*2 + hh;
  int beg = off[n], end = off[n+1];
  float a0=0.f, a1=0.f, a2=0.f, a3=0.f;
  int j = beg;
  for(; j+3 < end; j += 4){
    int i0=bucket[j], i1=bucket[j+1], i2=bucket[j+2], i3=bucket[j+3];
    a0 += x[i0*D+f]; a1 += x[i1*D+f]; a2 += x[i2*D+f]; a3 += x[i3*D+f];
  }
  for(; j < end; ++j) a0 += x[bucket[j]*D+f];
  int c = end - beg;
  mean[n*D + f] = (a0+a1+a2+a3) / (float)(c>1?c:1);
}

// ---- MFMA fused chain: G1 -> gelu -> {scores, G2} -> G3 ----
// 64 blocks x 256 thr (4 waves). Block owns rows r0..r0+15. Wave w owns
// cols [w*32,w*32+32) for G1/G3 and [w*96,w*96+96) for G2's N=384.
// Frags: A row = lane&15, B col = lane&15, k = (lane>>4)*8 + i (consistent
// permutation on both operands => correct for any hw k-order).
// C/D (m89-verified): col = lane&15, row = (lane>>4)*4 + reg.
__global__ __launch_bounds__(256) void k_mfma(
    const float* __restrict__ x, const float* __restrict__ mean,
    const float* __restrict__ Wl, const float* __restrict__ bl,
    const float* __restrict__ Wr,
    const float* __restrict__ W1, const float* __restrict__ b1,
    const float* __restrict__ W2, const float* __restrict__ b2,
    const float* __restrict__ Wp, const float* __restrict__ Wd,
    const float* __restrict__ bd, const int* __restrict__ deg,
    float* __restrict__ delta, float* __restrict__ res,
    float* __restrict__ scores, float* __restrict__ s1, float* __restrict__ s2)
{
  __shared__ __attribute__((aligned(16))) unsigned short xg[16][136]; // bf16 bits, 2-way banks
  __shared__ __attribute__((aligned(16))) unsigned short dr[16][136];
  int t = threadIdx.x;
  int w = t >> 6, l = t & 63;
  int lr = l & 15, lg = l >> 4;
  int r0 = blockIdx.x * 16;

  // ---- G1: x_gnn = mean@Wl^T + x@Wr^T + bl + x ; xg = gelu(x_gnn) ----
  short8 afr[8];
  {
    const float* mrow = mean + (size_t)(r0 + lr)*D + lg*8;
    const float* xrow = x    + (size_t)(r0 + lr)*D + lg*8;
    #pragma unroll
    for(int s = 0; s < 4; ++s) afr[s]   = ldfrag(mrow + s*32);
    #pragma unroll
    for(int s = 0; s < 4; ++s) afr[4+s] = ldfrag(xrow + s*32);
  }
  floatx4 acc0 = {0.f,0.f,0.f,0.f}, acc1 = {0.f,0.f,0.f,0.f};
  {
    const float* wl0 = Wl + (size_t)(w*32 + lr)*D + lg*8;
    const float* wl1 = Wl + (size_t)(w*32 + 16 + lr)*D + lg*8;
    const float* wr0 = Wr + (size_t)(w*32 + lr)*D + lg*8;
    const float* wr1 = Wr + (size_t)(w*32 + 16 + lr)*D + lg*8;
    #pragma unroll
    for(int s = 0; s < 4; ++s){
      acc0 = __builtin_amdgcn_mfma_f32_16x16x32_bf16(afr[s], ldfrag(wl0 + s*32), acc0, 0,0,0);
      acc1 = __builtin_amdgcn_mfma_f32_16x16x32_bf16(afr[s], ldfrag(wl1 + s*32), acc1, 0,0,0);
    }
    #pragma unroll
    for(int s = 0; s < 4; ++s){
      acc0 = __builtin_amdgcn_mfma_f32_16x16x32_bf16(afr[4+s], ldfrag(wr0 + s*32), acc0, 0,0,0);
      acc1 = __builtin_amdgcn_mfma_f32_16x16x32_bf16(afr[4+s], ldfrag(wr1 + s*32), acc1, 0,0,0);
    }
  }
  #pragma unroll
  for(int nf = 0; nf < 2; ++nf){
    int col = w*32 + nf*16 + lr;
    float blv = bl[col];
    floatx4 a = nf ? acc1 : acc0;
    #pragma unroll
    for(int rg = 0; rg < 4; ++rg){
      int row = lg*4 + rg;
      float v = a[rg] + blv + x[(size_t)(r0+row)*D + col];
      float g = 0.5f*v*(1.0f + erff(v*0.7071067811865475f));
      xg[row][col] = f2bf(g);
    }
  }
  __syncthreads();

  // A-frags of xg (shared by scores, G2)
  short8 ag[4];
  #pragma unroll
  for(int s = 0; s < 4; ++s) ag[s] = *(const short8*)&xg[lr][s*32 + lg*8];

  // ---- scores MLP via MFMA (wave 0 only): hidden = relu(xg@W1^T+b1); score=h@W2 ----
  if(w == 0){
    floatx4 sa0 = {0.f,0.f,0.f,0.f}, sa1 = {0.f,0.f,0.f,0.f};
    const float* w10 = W1 + (size_t)(lr)*D + lg*8;
    const float* w11 = W1 + (size_t)(16 + lr)*D + lg*8;
    #pragma unroll
    for(int s = 0; s < 4; ++s){
      sa0 = __builtin_amdgcn_mfma_f32_16x16x32_bf16(ag[s], ldfrag(w10 + s*32), sa0, 0,0,0);
      sa1 = __builtin_amdgcn_mfma_f32_16x16x32_bf16(ag[s], ldfrag(w11 + s*32), sa1, 0,0,0);
    }
    float b10 = b1[lr], b11 = b1[16+lr];
    float w20 = W2[lr], w21 = W2[16+lr];
    #pragma unroll
    for(int rg = 0; rg < 4; ++rg){
      float v = fmaxf(sa0[rg] + b10, 0.f)*w20 + fmaxf(sa1[rg] + b11, 0.f)*w21;
      v += __shfl_xor(v, 1); v += __shfl_xor(v, 2);
      v += __shfl_xor(v, 4); v += __shfl_xor(v, 8);
      if(lr == 0){
        int row = lg*4 + rg;
        scores[r0 + row] = v + b2[0] + (float)deg[r0 + row];
      }
    }
  }

  // ---- G2: proj = xg @ Wp-slices^T (N=384: delta_raw | Cs | res) ----
  floatx4 acc2[6];
  #pragma unroll
  for(int j = 0; j < 6; ++j) acc2[j] = floatx4{0.f,0.f,0.f,0.f};
  #pragma unroll
  for(int j = 0; j < 6; ++j){
    int ng = w*96 + j*16;
    // Wp rows: n<128 -> n (delta slice); n in [128,384) -> n+128 (skips dead _Bs slice)
    const float* bp = Wp + (size_t)((ng < 128 ? ng : ng + 128) + lr)*D + lg*8;
    #pragma unroll
    for(int s = 0; s < 4; ++s)
      acc2[j] = __builtin_amdgcn_mfma_f32_16x16x32_bf16(ag[s], ldfrag(bp + s*32), acc2[j], 0,0,0);
  }
  #pragma unroll
  for(int j = 0; j < 6; ++j){
    int ng = w*96 + j*16;
    if(ng < 128){                         // delta_raw -> LDS for G3
      #pragma unroll
      for(int rg = 0; rg < 4; ++rg) dr[lg*4+rg][ng+lr] = f2bf(acc2[j][rg]);
    } else if(ng < 256){                  // Cs -> S1/S2 reduction
      int h = ng - 128 + lr;
      float ls1 = 0.f, ls2 = 0.f;
      #pragma unroll
      for(int rg = 0; rg < 4; ++rg){
        float c = acc2[j][rg];
        ls1 += bf2f(xg[lg*4+rg][h]) * c;
        ls2 += c;
      }
      ls1 += __shfl_xor(ls1, 16); ls1 += __shfl_xor(ls1, 32);
      ls2 += __shfl_xor(ls2, 16); ls2 += __shfl_xor(ls2, 32);
      if(lg == 0){ atomicAdd(&s1[h], ls1); atomicAdd(&s2[h], ls2); }
    } else {                              // residual -> global
      int c = ng - 256 + lr;
      #pragma unroll
      for(int rg = 0; rg < 4; ++rg)
        res[(size_t)(r0 + lg*4 + rg)*D + c] = acc2[j][rg];
    }
  }
  __syncthreads();

  // ---- G3: delta = softplus(delta_raw @ Wd^T + bd) ----
  short8 ad[4];
  #pragma unroll
  for(int s = 0; s < 4; ++s) ad[s] = *(const short8*)&dr[lr][s*32 + lg*8];
  floatx4 acc3[2];
  acc3[0] = floatx4{0.f,0.f,0.f,0.f}; acc3[1] = floatx4{0.f,0.f,0.f,0.f};
  #pragma unroll
  for(int nf = 0; nf < 2; ++nf){
    const float* wd = Wd + (size_t)(w*32 + nf*16 + lr)*D + lg*8;
    #pragma unroll
    for(int s = 0; s < 4; ++s)
      acc3[nf] = __builtin_amdgcn_mfma_f32_16x16x32_bf16(ad[s], ldfrag(wd + s*32), acc3[nf], 0,0,0);
  }
  #pragma unroll
  for(int nf = 0; nf < 2; ++nf){
    int col = w*32 + nf*16 + lr;
    float bdv = bd[col];
    #pragma unroll
    for(int rg = 0; rg < 4; ++rg){
      float d2 = acc3[nf][rg] + bdv;
      float sp = (d2 > 20.f) ? d2 : log1pf(expf(d2));
      delta[(size_t)(r0 + lg*4 + rg)*D + col] = sp;
    }
  }
}

__device__ __forceinline__ unsigned long long shflx64(unsigned long long v, int mask){
  int lo = __shfl_xor((int)(v & 0xffffffffull), mask);
  int hi = __shfl_xor((int)(v >> 32), mask);
  return ((unsigned long long)(unsigned int)hi << 32) | (unsigned int)lo;
}

// ---- hybrid bitonic argsort: j>=64 via LDS+barrier, j<=32 in-register shfl ----
__global__ __launch_bounds__(1024) void k_sort(const float* __restrict__ scores, int* sidx){
  __shared__ unsigned long long keys[N];
  int t = threadIdx.x;
  unsigned int u = __float_as_uint(scores[t]);
  u = (u >> 31) ? ~u : (u | 0x80000000u);    // monotone float->uint (ascending)
  unsigned int ks = ~u;                       // descending score
  keys[t] = ((unsigned long long)ks << 32) | (unsigned int)t;
  __syncthreads();
  for(int k = 2; k <= N; k <<= 1){
    for(int j = k >> 1; j >= 64; j >>= 1){
      int ixj = t ^ j;
      if(ixj > t){
        bool up = ((t & k) == 0);
        unsigned long long a = keys[t], b = keys[ixj];
        if((a > b) == up){ keys[t] = b; keys[ixj] = a; }
      }
      __syncthreads();
    }
    unsigned long long kv = keys[t];
    bool up = ((t & k) == 0);
    for(int j = ((k>>1) < 32 ? (k>>1) : 32); j >= 1; j >>= 1){
      unsigned long long pv = shflx64(kv, j);
      bool lower = ((t & j) == 0);
      unsigned long long mn = kv < pv ? kv : pv;
      unsigned long long mx = kv < pv ? pv : kv;
      kv = (lower == up) ? mn : mx;
    }
    keys[t] = kv;
    __syncthreads();
  }
  sidx[t] = (int)(keys[t] & 0xFFFFFFFFu);
}

// ---- cumsum over sorted order, 4 heads/block; output pfx[l*D+h] ----
__global__ __launch_bounds__(1024) void k_cumsum(const float* __restrict__ delta,
     const int* __restrict__ sidx, const float* __restrict__ Bp, float* __restrict__ pfx){
  int t = threadIdx.x, h0 = blockIdx.x*4;
  int i = sidx[t];
  float4 dv = *(const float4*)&delta[i*D + h0];
  float4 bv = *(const float4*)&Bp[h0];
  float v0 = dv.x*bv.x, v1 = dv.y*bv.y, v2 = dv.z*bv.z, v3 = dv.w*bv.w;
  int lane = t & 63, w = t >> 6;
  #pragma unroll
  for(int o2 = 1; o2 < 64; o2 <<= 1){
    float n0 = __shfl_up(v0, o2, 64), n1 = __shfl_up(v1, o2, 64);
    float n2 = __shfl_up(v2, o2, 64), n3 = __shfl_up(v3, o2, 64);
    if(lane >= o2){ v0 += n0; v1 += n1; v2 += n2; v3 += n3; }
  }
  __shared__ float4 wsum[16];
  if(lane == 63) wsum[w] = make_float4(v0, v1, v2, v3);
  __syncthreads();
  float p0=0.f, p1=0.f, p2=0.f, p3=0.f;
  #pragma unroll
  for(int i2 = 0; i2 < 16; ++i2){
    float4 sv = wsum[i2];
    if(i2 < w){ p0 += sv.x; p1 += sv.y; p2 += sv.z; p3 += sv.w; }
  }
  float4 outv; outv.x = v0+p0; outv.y = v1+p1; outv.z = v2+p2; outv.w = v3+p3;
  *(float4*)&pfx[t*D + h0] = outv;
}

// ---- final: y + res*Dp, LayerNorm over D, un-permute, add x ----
__global__ __launch_bounds__(128) void k_final(
    const float* __restrict__ delta, const float* __restrict__ res,
    const float* __restrict__ pfx, const int* __restrict__ sidx,
    const float* __restrict__ s1, const float* __restrict__ s2,
    const float* __restrict__ A, const float* __restrict__ Bp,
    const float* __restrict__ Dp, const float* __restrict__ x,
    float* __restrict__ out){
  int l = blockIdx.x, h = threadIdx.x;
  int i = sidx[l];
  float dlt = delta[i*D + h];
  float dAv = expf(dlt * A[h]) * Bp[h];
  float o = dAv * s1[h] + pfx[l*D + h] * s2[h] + res[i*D + h] * Dp[0];
  __shared__ float sm1[2], sm2[2];
  float v = o;
  v += __shfl_down(v, 32); v += __shfl_down(v, 16); v += __shfl_down(v, 8);
  v += __shfl_down(v, 4);  v += __shfl_down(v, 2);  v += __shfl_down(v, 1);
  int wid = h >> 6, lane = h & 63;
  if(lane == 0) sm1[wid] = v;
  __syncthreads();
  float mean = (sm1[0] + sm1[1]) * (1.0f/(float)D);
  float cdev = o - mean;
  float cv = cdev * cdev;
  cv += __shfl_down(cv, 32); cv += __shfl_down(cv, 16); cv += __shfl_down(cv, 8);
  cv += __shfl_down(cv, 4);  cv += __shfl_down(cv, 2);  cv += __shfl_down(cv, 1);
  if(lane == 0) sm2[wid] = cv;
  __syncthreads();
  float var = (sm2[0] + sm2[1]) * (1.0f/(float)D);
  float nrm = cdev * rsqrtf(var + 1e-5f);
  out[i*D + h] = x[i*D + h] + nrm;
}

} // namespace

extern "C" void kernel_launch(void* const* d_in, const int* in_sizes, int n_in,
                              void* d_out, int out_size, void* d_ws, size_t ws_size,
                              hipStream_t stream){
  const float* x   = (const float*)d_in[0];
  const int*   ei  = (const int*)d_in[1];
  const float* Wl  = (const float*)d_in[2];
  const float* bl  = (const float*)d_in[3];
  const float* Wr  = (const float*)d_in[4];
  const float* W1  = (const float*)d_in[5];
  const float* b1  = (const float*)d_in[6];
  const float* W2  = (const float*)d_in[7];
  const float* b2  = (const float*)d_in[8];
  const float* Wp  = (const float*)d_in[9];
  const float* A   = (const float*)d_in[10];
  const float* Bp  = (const float*)d_in[11];
  const float* Dp  = (const float*)d_in[12];
  const float* Wd  = (const float*)d_in[13];
  const float* bd  = (const float*)d_in[14];

  char* ws = (char*)d_ws;
  size_t o = 0;
  auto alloc = [&](size_t bytes)->char*{
    char* p = ws + o;
    o = (o + bytes + 255) & ~(size_t)255;
    return p;
  };
  // zero-initialized region (one memset): S1, S2
  float* s1     = (float*)alloc(D*4);
  float* s2     = (float*)alloc(D*4);
  size_t zbytes = o;
  int*   off    = (int*)  alloc((N+1)*4);
  int*   deg    = (int*)  alloc(N*4);
  int*   bucket = (int*)  alloc(E*4);
  float* meanb  = (float*)alloc((size_t)N*D*4);
  float* scores = (float*)alloc(N*4);
  int*   sidx   = (int*)  alloc(N*4);
  float* delta  = (float*)alloc((size_t)N*D*4);
  float* res    = (float*)alloc((size_t)N*D*4);
  float* pfx    = (float*)alloc((size_t)N*D*4);
  (void)ws_size; (void)in_sizes; (void)n_in; (void)out_size;

  hipMemsetAsync(d_ws, 0, zbytes, stream);
  k_edges <<<1, 1024, 0, stream>>>(ei, off, deg, bucket);
  k_mean  <<<N/2, 256, 0, stream>>>(x, off, bucket, meanb);
  k_mfma  <<<N/16, 256, 0, stream>>>(x, meanb, Wl, bl, Wr, W1, b1, W2, b2, Wp, Wd, bd,
                                     deg, delta, res, scores, s1, s2);
  k_sort  <<<1, 1024, 0, stream>>>(scores, sidx);
  k_cumsum<<<D/4, 1024, 0, stream>>>(delta, sidx, Bp, pfx);
  k_final <<<N, 128, 0, stream>>>(delta, res, pfx, sidx, s1, s2, A, Bp, Dp, x, (float*)d_out);
}

// Round 8
// 72.697 us; speedup vs baseline: 1.7517x; 1.1808x over previous
//
#include <hip/hip_runtime.h>

namespace {
constexpr int N = 1024;
constexpr int D = 128;
constexpr int E = 32768;

using short8  = __attribute__((ext_vector_type(8))) short;
using floatx4 = __attribute__((ext_vector_type(4))) float;

__device__ __forceinline__ unsigned short f2bf(float f){
  unsigned int u = __float_as_uint(f);
  unsigned int r = (u + 0x7FFFu + ((u >> 16) & 1u)) >> 16;   // RTN-even
  return (unsigned short)r;
}
__device__ __forceinline__ float bf2f(unsigned short b){
  return __uint_as_float(((unsigned int)b) << 16);
}
// 8 consecutive f32 -> bf16x8 fragment
__device__ __forceinline__ short8 ldfrag(const float* p){
  float4 a = *(const float4*)p;
  float4 b = *(const float4*)(p + 4);
  short8 r;
  r[0]=(short)f2bf(a.x); r[1]=(short)f2bf(a.y); r[2]=(short)f2bf(a.z); r[3]=(short)f2bf(a.w);
  r[4]=(short)f2bf(b.x); r[5]=(short)f2bf(b.y); r[6]=(short)f2bf(b.z); r[7]=(short)f2bf(b.w);
  return r;
}

// ---- edge pass 1: counts + degrees (global int atomics, 128 blocks) ----
__global__ void k_edges1(const int* __restrict__ ei, int* cnt, int* deg){
  int e = blockIdx.x*256 + threadIdx.x;
  if(e < E){
    int s = ei[e], d = ei[E+e];
    atomicAdd(&cnt[d], 1);
    atomicAdd(&deg[s], 1);
    atomicAdd(&deg[d], 1);
  }
}

// ---- exclusive scan of cnt -> CSR offsets (wave shuffle scan) ----
__global__ __launch_bounds__(1024) void k_scan(const int* __restrict__ cnt, int* off, int* cur){
  int t = threadIdx.x;
  int v = cnt[t], own = v;
  int lane = t & 63, w = t >> 6;
  #pragma unroll
  for(int o2 = 1; o2 < 64; o2 <<= 1){
    int nb = __shfl_up(v, o2, 64);
    if(lane >= o2) v += nb;
  }
  __shared__ int wsum[16];
  if(lane == 63) wsum[w] = v;
  __syncthreads();
  int pref = 0;
  #pragma unroll
  for(int i = 0; i < 16; ++i){ int sv = wsum[i]; if(i < w) pref += sv; }
  int incl = v + pref, excl = incl - own;
  off[t] = excl; cur[t] = excl;
  if(t == N-1) off[N] = incl;
}

// ---- edge pass 2: fill buckets ----
__global__ void k_edges2(const int* __restrict__ ei, int* cur, int* bucket){
  int e = blockIdx.x*256 + threadIdx.x;
  if(e < E){
    int s = ei[e], d = ei[E+e];
    int p = atomicAdd(&cur[d], 1);
    bucket[p] = s;
  }
}

// ---- neighbor mean: 512 blocks x 256 thr, 2 nodes/block ----
__global__ __launch_bounds__(256) void k_mean(const float* __restrict__ x,
    const int* __restrict__ off, const int* __restrict__ bucket,
    float* __restrict__ mean){
  int t = threadIdx.x;
  int f = t & 127, hh = t >> 7;
  int n = blockIdx.x*2 + hh;
  int beg = off[n], end = off[n+1];
  float a0=0.f, a1=0.f, a2=0.f, a3=0.f;
  int j = beg;
  for(; j+3 < end; j += 4){
    int i0=bucket[j], i1=bucket[j+1], i2=bucket[j+2], i3=bucket[j+3];
    a0 += x[i0*D+f]; a1 += x[i1*D+f]; a2 += x[i2*D+f]; a3 += x[i3*D+f];
  }
  for(; j < end; ++j) a0 += x[bucket[j]*D+f];
  int c = end - beg;
  mean[n*D + f] = (a0+a1+a2+a3) / (float)(c>1?c:1);
}

// ============ MFMA tile kernels: 1 wave per 16x16 output tile ============
// Frags: A row = lane&15, B col = lane&15, k = (lane>>4)*8 + i (consistent
// permutation both operands). C/D: col = lane&15, row = (lane>>4)*4 + reg.

// ---- G1: xg = gelu(mean@Wl^T + x@Wr^T + bl + x), bf16 out ----
__global__ __launch_bounds__(64) void k_g1(
    const float* __restrict__ x, const float* __restrict__ mean,
    const float* __restrict__ Wl, const float* __restrict__ bl,
    const float* __restrict__ Wr, unsigned short* __restrict__ xg)
{
  int bid = blockIdx.x;             // 64 strips x 8 col-tiles
  int strip = bid >> 3, ct = bid & 7;
  int l = threadIdx.x, lr = l & 15, lg = l >> 4;
  int r0 = strip*16;

  const float* mrow = mean + (size_t)(r0+lr)*D + lg*8;
  const float* xrow = x    + (size_t)(r0+lr)*D + lg*8;
  short8 am[4], ax[4];
  #pragma unroll
  for(int s = 0; s < 4; ++s){ am[s] = ldfrag(mrow + s*32); ax[s] = ldfrag(xrow + s*32); }

  const float* wl = Wl + (size_t)(ct*16+lr)*D + lg*8;
  const float* wr = Wr + (size_t)(ct*16+lr)*D + lg*8;
  floatx4 acc = {0.f,0.f,0.f,0.f};
  #pragma unroll
  for(int s = 0; s < 4; ++s) acc = __builtin_amdgcn_mfma_f32_16x16x32_bf16(am[s], ldfrag(wl + s*32), acc, 0,0,0);
  #pragma unroll
  for(int s = 0; s < 4; ++s) acc = __builtin_amdgcn_mfma_f32_16x16x32_bf16(ax[s], ldfrag(wr + s*32), acc, 0,0,0);

  int col = ct*16 + lr;
  float blv = bl[col];
  #pragma unroll
  for(int rg = 0; rg < 4; ++rg){
    int row = lg*4 + rg;
    float v = acc[rg] + blv + x[(size_t)(r0+row)*D + col];
    float g = 0.5f*v*(1.0f + erff(v*0.7071067811865475f));
    xg[(size_t)(r0+row)*D + col] = f2bf(g);
  }
}

// ---- G2: 25 tiles/strip: 8 dr | 8 Cs->S1/S2 | 8 res | 1 scores ----
__global__ __launch_bounds__(64) void k_g2(
    const unsigned short* __restrict__ xg,
    const float* __restrict__ Wp, const float* __restrict__ W1,
    const float* __restrict__ b1, const float* __restrict__ W2,
    const float* __restrict__ b2, const int* __restrict__ deg,
    unsigned short* __restrict__ dr, float* __restrict__ res,
    float* __restrict__ s1, float* __restrict__ s2,
    float* __restrict__ scores)
{
  int bid = blockIdx.x;             // 64 strips x 25 tiles
  int strip = bid / 25, tt = bid - strip*25;
  int l = threadIdx.x, lr = l & 15, lg = l >> 4;
  int r0 = strip*16;

  const unsigned short* agp = xg + (size_t)(r0+lr)*D + lg*8;
  short8 ag[4];
  #pragma unroll
  for(int s = 0; s < 4; ++s) ag[s] = *(const short8*)(agp + s*32);

  if(tt < 24){
    int seg = tt >> 3, ctl = tt & 7;       // seg: 0=dr,1=Cs,2=res
    int wrow = (seg == 0) ? ctl*16 : (seg == 1) ? (2*D + ctl*16) : (3*D + ctl*16);
    const float* bp = Wp + (size_t)(wrow + lr)*D + lg*8;
    floatx4 acc = {0.f,0.f,0.f,0.f};
    #pragma unroll
    for(int s = 0; s < 4; ++s) acc = __builtin_amdgcn_mfma_f32_16x16x32_bf16(ag[s], ldfrag(bp + s*32), acc, 0,0,0);
    if(seg == 0){
      int col = ctl*16 + lr;
      #pragma unroll
      for(int rg = 0; rg < 4; ++rg) dr[(size_t)(r0+lg*4+rg)*D + col] = f2bf(acc[rg]);
    } else if(seg == 1){
      int h = ctl*16 + lr;
      float ls1 = 0.f, ls2 = 0.f;
      #pragma unroll
      for(int rg = 0; rg < 4; ++rg){
        float c = acc[rg];
        ls1 += bf2f(xg[(size_t)(r0+lg*4+rg)*D + h]) * c;
        ls2 += c;
      }
      ls1 += __shfl_xor(ls1, 16); ls1 += __shfl_xor(ls1, 32);
      ls2 += __shfl_xor(ls2, 16); ls2 += __shfl_xor(ls2, 32);
      if(lg == 0){ atomicAdd(&s1[h], ls1); atomicAdd(&s2[h], ls2); }
    } else {
      int col = ctl*16 + lr;
      #pragma unroll
      for(int rg = 0; rg < 4; ++rg) res[(size_t)(r0+lg*4+rg)*D + col] = acc[rg];
    }
  } else {
    // scores: hidden = relu(xg@W1^T + b1) (R=32); score = hidden@W2 + b2 + deg
    floatx4 sa0 = {0.f,0.f,0.f,0.f}, sa1 = {0.f,0.f,0.f,0.f};
    const float* w10 = W1 + (size_t)(lr)*D + lg*8;
    const float* w11 = W1 + (size_t)(16+lr)*D + lg*8;
    #pragma unroll
    for(int s = 0; s < 4; ++s){
      sa0 = __builtin_amdgcn_mfma_f32_16x16x32_bf16(ag[s], ldfrag(w10 + s*32), sa0, 0,0,0);
      sa1 = __builtin_amdgcn_mfma_f32_16x16x32_bf16(ag[s], ldfrag(w11 + s*32), sa1, 0,0,0);
    }
    float b10 = b1[lr], b11 = b1[16+lr];
    float w20 = W2[lr], w21 = W2[16+lr];
    #pragma unroll
    for(int rg = 0; rg < 4; ++rg){
      float v = fmaxf(sa0[rg] + b10, 0.f)*w20 + fmaxf(sa1[rg] + b11, 0.f)*w21;
      v += __shfl_xor(v, 1); v += __shfl_xor(v, 2);
      v += __shfl_xor(v, 4); v += __shfl_xor(v, 8);
      if(lr == 0){
        int row = lg*4 + rg;
        scores[r0 + row] = v + b2[0] + (float)deg[r0 + row];
      }
    }
  }
}

// ---- G3: delta = softplus(dr @ Wd^T + bd), f32 out ----
__global__ __launch_bounds__(64) void k_g3(
    const unsigned short* __restrict__ dr,
    const float* __restrict__ Wd, const float* __restrict__ bd,
    float* __restrict__ delta)
{
  int bid = blockIdx.x;             // 64 strips x 8 col-tiles
  int strip = bid >> 3, ct = bid & 7;
  int l = threadIdx.x, lr = l & 15, lg = l >> 4;
  int r0 = strip*16;

  const unsigned short* adp = dr + (size_t)(r0+lr)*D + lg*8;
  short8 ad[4];
  #pragma unroll
  for(int s = 0; s < 4; ++s) ad[s] = *(const short8*)(adp + s*32);

  const float* wd = Wd + (size_t)(ct*16+lr)*D + lg*8;
  floatx4 acc = {0.f,0.f,0.f,0.f};
  #pragma unroll
  for(int s = 0; s < 4; ++s) acc = __builtin_amdgcn_mfma_f32_16x16x32_bf16(ad[s], ldfrag(wd + s*32), acc, 0,0,0);

  int col = ct*16 + lr;
  float bdv = bd[col];
  #pragma unroll
  for(int rg = 0; rg < 4; ++rg){
    float d2 = acc[rg] + bdv;
    float sp = (d2 > 20.f) ? d2 : log1pf(expf(d2));
    delta[(size_t)(r0+lg*4+rg)*D + col] = sp;
  }
}

__device__ __forceinline__ unsigned long long shflx64(unsigned long long v, int mask){
  int lo = __shfl_xor((int)(v & 0xffffffffull), mask);
  int hi = __shfl_xor((int)(v >> 32), mask);
  return ((unsigned long long)(unsigned int)hi << 32) | (unsigned int)lo;
}

// ---- hybrid bitonic argsort: j>=64 via LDS+barrier, j<=32 in-register shfl ----
__global__ __launch_bounds__(1024) void k_sort(const float* __restrict__ scores, int* sidx){
  __shared__ unsigned long long keys[N];
  int t = threadIdx.x;
  unsigned int u = __float_as_uint(scores[t]);
  u = (u >> 31) ? ~u : (u | 0x80000000u);    // monotone float->uint (ascending)
  unsigned int ks = ~u;                       // descending score
  keys[t] = ((unsigned long long)ks << 32) | (unsigned int)t;
  __syncthreads();
  for(int k = 2; k <= N; k <<= 1){
    for(int j = k >> 1; j >= 64; j >>= 1){
      int ixj = t ^ j;
      if(ixj > t){
        bool up = ((t & k) == 0);
        unsigned long long a = keys[t], b = keys[ixj];
        if((a > b) == up){ keys[t] = b; keys[ixj] = a; }
      }
      __syncthreads();
    }
    unsigned long long kv = keys[t];
    bool up = ((t & k) == 0);
    for(int j = ((k>>1) < 32 ? (k>>1) : 32); j >= 1; j >>= 1){
      unsigned long long pv = shflx64(kv, j);
      bool lower = ((t & j) == 0);
      unsigned long long mn = kv < pv ? kv : pv;
      unsigned long long mx = kv < pv ? pv : kv;
      kv = (lower == up) ? mn : mx;
    }
    keys[t] = kv;
    __syncthreads();
  }
  sidx[t] = (int)(keys[t] & 0xFFFFFFFFu);
}

// ---- cumsum over sorted order, 4 heads/block; output pfx[l*D+h] ----
__global__ __launch_bounds__(1024) void k_cumsum(const float* __restrict__ delta,
     const int* __restrict__ sidx, const float* __restrict__ Bp, float* __restrict__ pfx){
  int t = threadIdx.x, h0 = blockIdx.x*4;
  int i = sidx[t];
  float4 dv = *(const float4*)&delta[i*D + h0];
  float4 bv = *(const float4*)&Bp[h0];
  float v0 = dv.x*bv.x, v1 = dv.y*bv.y, v2 = dv.z*bv.z, v3 = dv.w*bv.w;
  int lane = t & 63, w = t >> 6;
  #pragma unroll
  for(int o2 = 1; o2 < 64; o2 <<= 1){
    float n0 = __shfl_up(v0, o2, 64), n1 = __shfl_up(v1, o2, 64);
    float n2 = __shfl_up(v2, o2, 64), n3 = __shfl_up(v3, o2, 64);
    if(lane >= o2){ v0 += n0; v1 += n1; v2 += n2; v3 += n3; }
  }
  __shared__ float4 wsum[16];
  if(lane == 63) wsum[w] = make_float4(v0, v1, v2, v3);
  __syncthreads();
  float p0=0.f, p1=0.f, p2=0.f, p3=0.f;
  #pragma unroll
  for(int i2 = 0; i2 < 16; ++i2){
    float4 sv = wsum[i2];
    if(i2 < w){ p0 += sv.x; p1 += sv.y; p2 += sv.z; p3 += sv.w; }
  }
  float4 outv; outv.x = v0+p0; outv.y = v1+p1; outv.z = v2+p2; outv.w = v3+p3;
  *(float4*)&pfx[t*D + h0] = outv;
}

// ---- final: y + res*Dp, LayerNorm over D, un-permute, add x ----
__global__ __launch_bounds__(128) void k_final(
    const float* __restrict__ delta, const float* __restrict__ res,
    const float* __restrict__ pfx, const int* __restrict__ sidx,
    const float* __restrict__ s1, const float* __restrict__ s2,
    const float* __restrict__ A, const float* __restrict__ Bp,
    const float* __restrict__ Dp, const float* __restrict__ x,
    float* __restrict__ out){
  int l = blockIdx.x, h = threadIdx.x;
  int i = sidx[l];
  float dlt = delta[i*D + h];
  float dAv = expf(dlt * A[h]) * Bp[h];
  float o = dAv * s1[h] + pfx[l*D + h] * s2[h] + res[i*D + h] * Dp[0];
  __shared__ float sm1[2], sm2[2];
  float v = o;
  v += __shfl_down(v, 32); v += __shfl_down(v, 16); v += __shfl_down(v, 8);
  v += __shfl_down(v, 4);  v += __shfl_down(v, 2);  v += __shfl_down(v, 1);
  int wid = h >> 6, lane = h & 63;
  if(lane == 0) sm1[wid] = v;
  __syncthreads();
  float mean = (sm1[0] + sm1[1]) * (1.0f/(float)D);
  float cdev = o - mean;
  float cv = cdev * cdev;
  cv += __shfl_down(cv, 32); cv += __shfl_down(cv, 16); cv += __shfl_down(cv, 8);
  cv += __shfl_down(cv, 4);  cv += __shfl_down(cv, 2);  cv += __shfl_down(cv, 1);
  if(lane == 0) sm2[wid] = cv;
  __syncthreads();
  float var = (sm2[0] + sm2[1]) * (1.0f/(float)D);
  float nrm = cdev * rsqrtf(var + 1e-5f);
  out[i*D + h] = x[i*D + h] + nrm;
}

} // namespace

extern "C" void kernel_launch(void* const* d_in, const int* in_sizes, int n_in,
                              void* d_out, int out_size, void* d_ws, size_t ws_size,
                              hipStream_t stream){
  const float* x   = (const float*)d_in[0];
  const int*   ei  = (const int*)d_in[1];
  const float* Wl  = (const float*)d_in[2];
  const float* bl  = (const float*)d_in[3];
  const float* Wr  = (const float*)d_in[4];
  const float* W1  = (const float*)d_in[5];
  const float* b1  = (const float*)d_in[6];
  const float* W2  = (const float*)d_in[7];
  const float* b2  = (const float*)d_in[8];
  const float* Wp  = (const float*)d_in[9];
  const float* A   = (const float*)d_in[10];
  const float* Bp  = (const float*)d_in[11];
  const float* Dp  = (const float*)d_in[12];
  const float* Wd  = (const float*)d_in[13];
  const float* bd  = (const float*)d_in[14];

  char* ws = (char*)d_ws;
  size_t o = 0;
  auto alloc = [&](size_t bytes)->char*{
    char* p = ws + o;
    o = (o + bytes + 255) & ~(size_t)255;
    return p;
  };
  // zero-initialized region (one memset): s1, s2, cnt, deg
  float* s1     = (float*)alloc(D*4);
  float* s2     = (float*)alloc(D*4);
  int*   cnt    = (int*)  alloc(N*4);
  int*   deg    = (int*)  alloc(N*4);
  size_t zbytes = o;
  int*   off    = (int*)  alloc((N+1)*4);
  int*   cur    = (int*)  alloc(N*4);
  int*   bucket = (int*)  alloc(E*4);
  float* meanb  = (float*)alloc((size_t)N*D*4);
  unsigned short* xg = (unsigned short*)alloc((size_t)N*D*2);
  unsigned short* dr = (unsigned short*)alloc((size_t)N*D*2);
  float* scores = (float*)alloc(N*4);
  int*   sidx   = (int*)  alloc(N*4);
  float* delta  = (float*)alloc((size_t)N*D*4);
  float* res    = (float*)alloc((size_t)N*D*4);
  float* pfx    = (float*)alloc((size_t)N*D*4);
  (void)ws_size; (void)in_sizes; (void)n_in; (void)out_size;

  hipMemsetAsync(d_ws, 0, zbytes, stream);
  k_edges1<<<(E+255)/256, 256, 0, stream>>>(ei, cnt, deg);
  k_scan  <<<1, 1024, 0, stream>>>(cnt, off, cur);
  k_edges2<<<(E+255)/256, 256, 0, stream>>>(ei, cur, bucket);
  k_mean  <<<N/2, 256, 0, stream>>>(x, off, bucket, meanb);
  k_g1    <<<64*8, 64, 0, stream>>>(x, meanb, Wl, bl, Wr, xg);
  k_g2    <<<64*25, 64, 0, stream>>>(xg, Wp, W1, b1, W2, b2, deg, dr, res, s1, s2, scores);
  k_g3    <<<64*8, 64, 0, stream>>>(dr, Wd, bd, delta);
  k_sort  <<<1, 1024, 0, stream>>>(scores, sidx);
  k_cumsum<<<D/4, 1024, 0, stream>>>(delta, sidx, Bp, pfx);
  k_final <<<N, 128, 0, stream>>>(delta, res, pfx, sidx, s1, s2, A, Bp, Dp, x, (float*)d_out);
}